// Round 1
// baseline (491.825 us; speedup 1.0000x reference)
//
#include <hip/hip_runtime.h>

#define NIMG 512
#define H 64
#define W 64
#define C 32
#define HW (H * W)
#define TPB 512

typedef _Float16 half8 __attribute__((ext_vector_type(8)));
typedef _Float16 half4v __attribute__((ext_vector_type(4)));

__device__ __forceinline__ int iclamp(int v, int lo, int hi) {
    return v < lo ? lo : (v > hi ? hi : v);
}

__device__ __forceinline__ half8 splat8(_Float16 x) {
    half8 v = {x, x, x, x, x, x, x, x};
    return v;
}

// One block = (image n, channel-octet oct). The 64x64x8 fp32 source slice is
// streamed (coalesced) from HBM and staged in LDS as fp16 (64 KiB -> 2
// blocks/CU, 16 waves/CU). All 4-corner gathers then hit LDS (1x
// ds_read_b128 per corner) instead of scattered 128B HBM/L2 lines.
//
// XCD pinning: assuming blockIdx%8 round-robins XCDs, the 4 sibling
// octet-blocks of an image get the same (b&7) and adjacent dispatch slots,
// so the full 128B pixel lines they jointly consume are fetched from HBM
// once and shared in that XCD's L2. Heuristic only; correctness independent.
__global__ __launch_bounds__(TPB) void stn_bilinear_lds_kernel(
    const float* __restrict__ X,       // (N, H, W, C) fp32
    const float* __restrict__ theta,   // (N, 6) fp32
    float* __restrict__ out)           // (N, H, W, C) fp32
{
    __shared__ _Float16 s[HW * 8];     // 64 KiB: s[p*8 + c], p = y*W + x

    const int b   = blockIdx.x;
    const int xcd = b & 7;
    const int sb  = b >> 3;            // 0..255
    const int oct = sb & 3;            // channel octet 0..3
    const int n   = xcd + ((sb >> 2) << 3);  // image 0..511
    const int tid = threadIdx.x;

    // Per-image affine params (uniform; scalar loads). Load early so the
    // s_load latency hides under staging.
    const float* th = theta + n * 6;
    const double a00 = (double)th[0], a01 = (double)th[1], a02 = (double)th[2];
    const double a10 = (double)th[3], a11 = (double)th[4], a12 = (double)th[5];

    const float* img = X + (size_t)n * (HW * C) + oct * 8;

    // ---- Stage: global fp32 (sequential-ish, 32B per 128B line; siblings
    // cover the rest) -> LDS fp16. 16 independent iterations/thread.
    for (int it = tid; it < HW * 2; it += TPB) {
        const int p  = it >> 1;        // pixel
        const int hf = it & 1;         // which 4-channel half of the octet
        const float4 v = *(const float4*)(img + (size_t)p * C + hf * 4);
        half4v hv = {( _Float16)v.x, (_Float16)v.y, (_Float16)v.z, (_Float16)v.w};
        *(half4v*)&s[p * 8 + hf * 4] = hv;   // 8B write, contiguous per wave
    }

    __syncthreads();

    // np.linspace(-1, 1, 64) semantics: step = 2/63, endpoint exact 1.0.
    const double step = 2.0 / 63.0;

    float* outb = out + (size_t)n * (HW * C) + oct * 8;

    // ---- Compute: 8 pixels/thread, coords in fp64 (identical numerics to
    // the passing kernel), blend in packed fp16 from LDS.
    for (int it = tid; it < HW; it += TPB) {
        const int row = it >> 6;
        const int col = it & 63;

        const double xj = (col == W - 1) ? 1.0 : ((double)col * step - 1.0);
        const double yi = (row == H - 1) ? 1.0 : ((double)row * step - 1.0);

        const double gs0 = (a00 * xj + a01 * yi) + a02;
        const double gs1 = (a10 * xj + a11 * yi) + a12;
        const double gx = (double)W * (gs0 + 1.0) * 0.5;
        const double gy = (double)H * (gs1 + 1.0) * 0.5;

        double fx = floor(gx);
        double fy = floor(gy);
        fx = fmin(fmax(fx, -1.0e6), 1.0e6);  // defensive: keep int cast defined
        fy = fmin(fmax(fy, -1.0e6), 1.0e6);
        const int x0i = (int)fx;
        const int y0i = (int)fy;

        const int X0 = iclamp(x0i,     0, W - 1);
        const int X1 = iclamp(x0i + 1, 0, W - 1);
        const int Y0 = iclamp(y0i,     0, H - 1);
        const int Y1 = iclamp(y0i + 1, 0, H - 1);

        float wax = (float)((double)X1 - gx);
        float wbx = (float)(gx - (double)X0);
        float way = (float)((double)Y1 - gy);
        float wby = (float)(gy - (double)Y0);

        // Clamped axis => both corners identical and the exact weight sum is
        // (X1-X0)==0; the reference's fp32 pairing cancels to <=1e-4, so
        // emit exactly 0 by zeroing the axis weights. This also bounds all
        // weights to [0,1], keeping the fp16 blend well-conditioned (no
        // large-|gx| cancellation in half precision).
        if (X0 == X1) { wax = 0.0f; wbx = 0.0f; }
        if (Y0 == Y1) { way = 0.0f; wby = 0.0f; }

        const half8 A  = *(const half8*)&s[(Y0 * W + X0) * 8];
        const half8 Bv = *(const half8*)&s[(Y1 * W + X0) * 8];
        const half8 Cv = *(const half8*)&s[(Y0 * W + X1) * 8];
        const half8 Dv = *(const half8*)&s[(Y1 * W + X1) * 8];

        const half8 vway = splat8((_Float16)way);
        const half8 vwby = splat8((_Float16)wby);
        const half8 vwax = splat8((_Float16)wax);
        const half8 vwbx = splat8((_Float16)wbx);

        const half8 left  = A  * vway + Bv * vwby;
        const half8 right = Cv * vway + Dv * vwby;
        const half8 res   = left * vwax + right * vwbx;

        float rf[8];
#pragma unroll
        for (int k = 0; k < 8; ++k) rf[k] = (float)res[k];

        float* po = outb + (size_t)it * C;
        *(float4*)(po)     = make_float4(rf[0], rf[1], rf[2], rf[3]);
        *(float4*)(po + 4) = make_float4(rf[4], rf[5], rf[6], rf[7]);
    }
}

extern "C" void kernel_launch(void* const* d_in, const int* in_sizes, int n_in,
                              void* d_out, int out_size, void* d_ws, size_t ws_size,
                              hipStream_t stream) {
    const float* X     = (const float*)d_in[0];
    const float* theta = (const float*)d_in[1];
    float* out         = (float*)d_out;

    const int blocks = NIMG * 4;  // 2048 blocks: (image, channel-octet)
    hipLaunchKernelGGL(stn_bilinear_lds_kernel, dim3(blocks), dim3(TPB), 0, stream,
                       X, theta, out);
}